// Round 11
// baseline (272.898 us; speedup 1.0000x reference)
//
#include <hip/hip_runtime.h>
#include <math.h>

// B=4, O=8, C=256, HID=128, H=W=64, STEPS=2
// m97-structure MFMA conv (glds dbuf staging, 1 barrier/chunk) at the known
// ~874TF plateau. This round removes the combine_sum RMW passes:
//   enc:   relu(conv(feats,Wf) [8 fp16 kz-partials] + conv(mask,Wm) + b)
//   per gcn step: sharedconv USum*W2 -> 4 fp16 kz-partials;
//                 objconv s_i*(W1-W2) with FUSED epilogue
//                   S = relu(raw + sum4(U2 partials) + b)  (writes final S);
//                 sum8 S -> USum (step 1 only).
//   ro:    sigmoid(conv(feats,Wa) + conv(s,Wb) + b), reg-resident weights.
// Activations fp16 chunked HWC: x[img][cc][px][ci32] (4KB DMA-able slabs).

typedef unsigned short ushort_t;
typedef _Float16 f16x8 __attribute__((ext_vector_type(8)));
typedef float f32x4 __attribute__((ext_vector_type(4)));

#define GLDS(gsrc, ldst)                                                      \
    __builtin_amdgcn_global_load_lds(                                         \
        (const __attribute__((address_space(1))) unsigned int*)(gsrc),        \
        (__attribute__((address_space(3))) unsigned int*)(ldst), 16, 0, 0)

__device__ __forceinline__ ushort_t f2h(float f) {
    _Float16 h = (_Float16)f;
    return *(ushort_t*)&h;
}
__device__ __forceinline__ float h2f(ushort_t u) {
    _Float16 h = *(_Float16*)&u;
    return (float)h;
}

// ---- merged prep: blocks <1024: feats CHW->chunked HWC; rest: weight packing
__global__ __launch_bounds__(256) void prep_all(
    const float* __restrict__ feats, const float* __restrict__ enc_w,
    const float* __restrict__ gcn_w, const float* __restrict__ ro_w,
    ushort_t* __restrict__ featsT, ushort_t* __restrict__ WencF,
    ushort_t* __restrict__ WgcnS, ushort_t* __restrict__ WgcnD,
    ushort_t* __restrict__ WroQ, ushort_t* __restrict__ WroS)
{
    __shared__ float tile[64][65];
    int bid = blockIdx.x, t = threadIdx.x;
    if (bid < 1024) {                 // feats transform: pt|ct|img
        int pt = bid & 63, ct = (bid >> 6) & 3, img = bid >> 8;
        int px_l = t & 63;
        const float* src = feats + ((size_t)img * 256 + ct * 64) * 4096 + pt * 64;
#pragma unroll
        for (int j = 0; j < 16; ++j) {
            int ci_l = (t >> 6) + j * 4;
            tile[px_l][ci_l] = src[(size_t)ci_l * 4096 + px_l];
        }
        __syncthreads();
        int px = t >> 2;
#pragma unroll
        for (int j = 0; j < 2; ++j) {
            int c8 = ((t & 3) + j * 4) * 8;
            uint4 v; ushort_t* pv = (ushort_t*)&v;
#pragma unroll
            for (int k = 0; k < 8; ++k) pv[k] = f2h(tile[px][c8 + k]);
            int cc = ct * 2 + (c8 >> 5);
            *(uint4*)(featsT + ((size_t)img * 8 + cc) * 131072 +
                      (size_t)(pt * 64 + px) * 32 + (c8 & 31)) = v;
        }
        return;
    }
    int i = (bid - 1024) * 256 + t;
    if (i < 294912) {                 // WencF[t][cc8][co128][ci32]
        int ci32 = i & 31, co = (i >> 5) & 127, tc = i >> 12;
        int tt = tc >> 3, cc = tc & 7, ci = cc * 32 + ci32;
        WencF[i] = f2h(enc_w[(co * 257 + ci) * 9 + tt]);
    } else if (i < 442368) {          // WgcnS[t][cc4][co128][ci32]
        int j = i - 294912;
        int ci32 = j & 31, co = (j >> 5) & 127, tc = j >> 12;
        int tt = tc >> 2, cc = tc & 3, ci = cc * 32 + ci32;
        WgcnS[j] = f2h(gcn_w[(co * 256 + 128 + ci) * 9 + tt]);
    } else if (i < 589824) {          // WgcnD = W1 - W2
        int j = i - 442368;
        int ci32 = j & 31, co = (j >> 5) & 127, tc = j >> 12;
        int tt = tc >> 2, cc = tc & 3, ci = cc * 32 + ci32;
        WgcnD[j] = f2h(gcn_w[(co * 256 + ci) * 9 + tt] -
                       gcn_w[(co * 256 + 128 + ci) * 9 + tt]);
    } else if (i < 592128) {          // WroQ[8cc][4q][9t][8k]
        int j = i - 589824;
        int k = j & 7, r = j >> 3;
        int tt = r % 9, cq = r / 9, q = cq & 3, cc = cq >> 2;
        WroQ[j] = f2h(ro_w[(cc * 32 + q * 8 + k) * 9 + tt]);
    } else if (i < 593280) {          // WroS[4cc][4q][9t][8k]
        int j = i - 592128;
        int k = j & 7, r = j >> 3;
        int tt = r % 9, cq = r / 9, q = cq & 3, cc = cq >> 2;
        WroS[j] = f2h(ro_w[(256 + cc * 32 + q * 8 + k) * 9 + tt]);
    }
}

// ---- conv (m97 structure). grid (32 rowpairs, nimg, kz). Block: 128co x 128px,
// 4 waves (cg,pg); wave 64co x 64px. Out: fp16 chunked raw at slot kz*gridDim.y+img.
// FUSE: epilogue = relu(raw + sum4(addp partials) + bias) (gcn object conv).
template<int NCCBLK, bool FUSE>
__global__ __launch_bounds__(256, 3) void conv_k(
    const ushort_t* __restrict__ x, const ushort_t* __restrict__ W,
    ushort_t* __restrict__ out,
    const ushort_t* __restrict__ addp, const float* __restrict__ bias,
    int ncc_img)
{
    __shared__ ushort_t raw[25088];           // 50176 B
    ushort_t* xs = raw;                       // 2 x [4 rows][66 cols][32ci]
    ushort_t* wlds = raw + 16896;             // 2 x [128 co][32ci]
    ushort_t* eb16 = raw;                     // epilogue overlay [64][136]

    const int rp = blockIdx.x, img = blockIdx.y, kz = blockIdx.z;
    const int row0 = rp * 2;
    const int cc0 = kz * NCCBLK;
    const int nchunk = 9 * NCCBLK;
    const int tid = threadIdx.x;
    const int w = tid >> 6, lane = tid & 63, lq = lane >> 4, lr = lane & 15;
    const int cg = w >> 1, pg = w & 1;

    const ushort_t* xb = x + (size_t)img * ncc_img * 131072;
    const int aoff0 = (cg * 64 + lr) * 32 + lq * 8;

    // zero halo columns (0 and 65) of both act buffers, once
    if (tid < 64) {
        int b = tid >> 5, r = (tid >> 3) & 3, c = (tid >> 2) & 1, s = tid & 3;
        *(uint4*)(xs + b * 8448 + r * 2112 + (c ? 65 : 0) * 32 + s * 8) =
            make_uint4(0, 0, 0, 0);
    }

    f32x4 acc[4][4];
#pragma unroll
    for (int a = 0; a < 4; ++a)
#pragma unroll
        for (int p = 0; p < 4; ++p) acc[a][p] = (f32x4){0.f, 0.f, 0.f, 0.f};

    const int gy = row0 - 1 + w;
    const bool row_ok = (unsigned)gy < 64u;
#define STAGE_ACT(cc_, buf_)                                                    \
    {                                                                           \
        ushort_t* dst = xs + (buf_) * 8448 + w * 2112 + 32;                     \
        if (row_ok) {                                                           \
            const ushort_t* src = xb + (size_t)(cc_) * 131072 + (size_t)gy * 2048; \
            GLDS(src + 0 * 512 + lane * 8, dst + 0 * 512);                      \
            GLDS(src + 1 * 512 + lane * 8, dst + 1 * 512);                      \
            GLDS(src + 2 * 512 + lane * 8, dst + 2 * 512);                      \
            GLDS(src + 3 * 512 + lane * 8, dst + 3 * 512);                      \
        } else {                                                                \
            *(uint4*)(dst + 0 * 512 + lane * 8) = make_uint4(0, 0, 0, 0);       \
            *(uint4*)(dst + 1 * 512 + lane * 8) = make_uint4(0, 0, 0, 0);       \
            *(uint4*)(dst + 2 * 512 + lane * 8) = make_uint4(0, 0, 0, 0);       \
            *(uint4*)(dst + 3 * 512 + lane * 8) = make_uint4(0, 0, 0, 0);       \
        }                                                                       \
    }
#define STAGE_W(t_, cc_, buf_)                                                  \
    {                                                                           \
        const ushort_t* src = W + ((size_t)((t_) * ncc_img + (cc_)) * 4096);    \
        ushort_t* dst = wlds + (buf_) * 4096;                                   \
        GLDS(src + (w * 2 + 0) * 512 + lane * 8, dst + (w * 2 + 0) * 512);      \
        GLDS(src + (w * 2 + 1) * 512 + lane * 8, dst + (w * 2 + 1) * 512);      \
    }

    STAGE_ACT(cc0, 0);
    STAGE_W(0, cc0, 0);

    int kc = 0;
#pragma unroll
    for (int ccl = 0; ccl < NCCBLK; ++ccl) {
        const int cc = cc0 + ccl;
        const int xbuf = ccl & 1;
#pragma unroll
        for (int t = 0; t < 9; ++t, ++kc) {
            __syncthreads();
            if (kc + 1 < nchunk) {
                if (t == 8) {
                    STAGE_W(0, cc + 1, (kc + 1) & 1);
                    STAGE_ACT(cc + 1, (ccl + 1) & 1);
                } else {
                    STAGE_W(t + 1, cc, (kc + 1) & 1);
                }
            }
            const int dy = t / 3, dx = t - 3 * dy;
            const ushort_t* wl = wlds + (kc & 1) * 4096 + aoff0;
            const ushort_t* xl = xs + xbuf * 8448 + (pg + dy) * 2112 + (dx + lr) * 32 + lq * 8;
            f16x8 A0 = *(const f16x8*)(wl);
            f16x8 A1 = *(const f16x8*)(wl + 512);
            f16x8 A2 = *(const f16x8*)(wl + 1024);
            f16x8 A3 = *(const f16x8*)(wl + 1536);
#pragma unroll
            for (int p = 0; p < 4; ++p) {
                f16x8 Bf = *(const f16x8*)(xl + p * 512);
                acc[0][p] = __builtin_amdgcn_mfma_f32_16x16x32_f16(A0, Bf, acc[0][p], 0, 0, 0);
                acc[1][p] = __builtin_amdgcn_mfma_f32_16x16x32_f16(A1, Bf, acc[1][p], 0, 0, 0);
                acc[2][p] = __builtin_amdgcn_mfma_f32_16x16x32_f16(A2, Bf, acc[2][p], 0, 0, 0);
                acc[3][p] = __builtin_amdgcn_mfma_f32_16x16x32_f16(A3, Bf, acc[3][p], 0, 0, 0);
            }
        }
    }

    // ---- epilogue via LDS transpose, fp16 chunked out
    ushort_t* obase = out + (size_t)(kz * gridDim.y + img) * 524288;
    const int b4 = img >> 3;                  // batch (FUSE only)
#pragma unroll
    for (int r = 0; r < 2; ++r) {
        __syncthreads();
        if (pg == r) {
#pragma unroll
            for (int cf = 0; cf < 4; ++cf)
#pragma unroll
                for (int pf = 0; pf < 4; ++pf) {
                    int px = pf * 16 + lr;
                    int co_l = cg * 64 + cf * 16 + lq * 4;
                    ushort_t pk[4];
#pragma unroll
                    for (int j = 0; j < 4; ++j) pk[j] = f2h(acc[cf][pf][j]);
                    *(uint2*)(eb16 + px * 136 + co_l) = *(uint2*)pk;
                }
        }
        __syncthreads();
#pragma unroll
        for (int k2 = 0; k2 < 4; ++k2) {
            int i = tid + k2 * 256;
            int px = i >> 4, c16 = i & 15;
            int pxg = (row0 + r) * 64 + px;
            size_t coff = (size_t)(c16 >> 2) * 131072 + (size_t)pxg * 32 + (c16 & 3) * 8;
            uint4 v = *(uint4*)(eb16 + px * 136 + c16 * 8);
            if constexpr (FUSE) {
                const ushort_t* vp = (const ushort_t*)&v;
                float vv[8];
#pragma unroll
                for (int k = 0; k < 8; ++k) vv[k] = h2f(vp[k]) + bias[c16 * 8 + k];
#pragma unroll
                for (int p = 0; p < 4; ++p) {
                    uint4 av = *(const uint4*)(addp + (size_t)(p * 4 + b4) * 524288 + coff);
                    const ushort_t* ap = (const ushort_t*)&av;
#pragma unroll
                    for (int k = 0; k < 8; ++k) vv[k] += h2f(ap[k]);
                }
                uint4 sv; ushort_t* sp = (ushort_t*)&sv;
#pragma unroll
                for (int k = 0; k < 8; ++k) sp[k] = f2h(fmaxf(vv[k], 0.f));
                *(uint4*)(obase + coff) = sv;
            } else {
                *(uint4*)(obase + coff) = v;
            }
        }
    }
#undef STAGE_ACT
#undef STAGE_W
}

// ---- sum over 8 objects: S[32][4cc][4096][32] -> USum[4][4cc][4096][32]
// thread i = b(2)|cc(2)|px(12)|s(2): wave covers 16px x 4units = 1KB contig/obj
__global__ __launch_bounds__(256) void sum8(const ushort_t* __restrict__ S,
                                            ushort_t* __restrict__ USum)
{
    int i = blockIdx.x * 256 + threadIdx.x;
    int s = i & 3, px = (i >> 2) & 4095, cc = (i >> 14) & 3, b = i >> 16;
    size_t coff = (size_t)cc * 131072 + (size_t)px * 32 + s * 8;
    const ushort_t* p = S + (size_t)b * 8 * 524288 + coff;
    float v[8] = {0, 0, 0, 0, 0, 0, 0, 0};
#pragma unroll
    for (int o = 0; o < 8; ++o) {
        uint4 xv = *(const uint4*)(p + (size_t)o * 524288);
        const ushort_t* xp = (const ushort_t*)&xv;
#pragma unroll
        for (int k = 0; k < 8; ++k) v[k] += h2f(xp[k]);
    }
    uint4 sv; ushort_t* sp = (ushort_t*)&sv;
#pragma unroll
    for (int k = 0; k < 8; ++k) sp[k] = f2h(v[k]);
    *(uint4*)(USum + (size_t)b * 524288 + coff) = sv;
}

// ---- encoder per-object part + object-sum (8 fp16 kz-partials in)
// thread i = b(2)|cc(2)|px(12)|s(2) (coalesced); co = cc*32 + s*8 + k
__global__ __launch_bounds__(256) void enc_obj_sum(
    const float* __restrict__ masks, const float* __restrict__ enc_w,
    const float* __restrict__ enc_b, const ushort_t* __restrict__ U1p,
    ushort_t* __restrict__ S, ushort_t* __restrict__ USum)
{
    int i = blockIdx.x * 256 + threadIdx.x;
    int s = i & 3, px = (i >> 2) & 4095, cc = (i >> 14) & 3, b = i >> 16;
    int co = cc * 32 + s * 8;
    int y = px >> 6, xx = px & 63;
    size_t coff = (size_t)cc * 131072 + (size_t)px * 32 + s * 8;
    float base[8];
#pragma unroll
    for (int k = 0; k < 8; ++k) base[k] = enc_b[co + k];
#pragma unroll
    for (int p = 0; p < 8; ++p) {
        uint4 v = *(const uint4*)(U1p + (size_t)(p * 4 + b) * 524288 + coff);
        const ushort_t* vp = (const ushort_t*)&v;
#pragma unroll
        for (int k = 0; k < 8; ++k) base[k] += h2f(vp[k]);
    }
    float wm[8][9];
#pragma unroll
    for (int k = 0; k < 8; ++k) {
        const float* wp = enc_w + (size_t)((co + k) * 257 + 256) * 9;
#pragma unroll
        for (int t = 0; t < 9; ++t) wm[k][t] = wp[t];
    }
    float sacc[8] = {0, 0, 0, 0, 0, 0, 0, 0};
#pragma unroll
    for (int o = 0; o < 8; ++o) {
        const float* m = masks + (size_t)(b * 8 + o) * 4096;
        float mt[9];
#pragma unroll
        for (int dy = 0; dy < 3; ++dy)
#pragma unroll
            for (int dx = 0; dx < 3; ++dx) {
                int gy_ = y + dy - 1, gx = xx + dx - 1;
                mt[dy * 3 + dx] =
                    ((unsigned)gy_ < 64u && (unsigned)gx < 64u) ? m[gy_ * 64 + gx] : 0.f;
            }
        uint4 sv; ushort_t* sp = (ushort_t*)&sv;
#pragma unroll
        for (int k = 0; k < 8; ++k) {
            float acc = base[k];
#pragma unroll
            for (int t = 0; t < 9; ++t) acc = fmaf(mt[t], wm[k][t], acc);
            acc = fmaxf(acc, 0.f);
            sacc[k] += acc;
            sp[k] = f2h(acc);
        }
        *(uint4*)(S + (size_t)(b * 8 + o) * 524288 + coff) = sv;
    }
    uint4 sv; ushort_t* sp = (ushort_t*)&sv;
#pragma unroll
    for (int k = 0; k < 8; ++k) sp[k] = f2h(sacc[k]);
    *(uint4*)(USum + (size_t)b * 524288 + coff) = sv;
}

// ---- readout shared part: thread = 8 ci x 9 taps, weights in regs
__global__ __launch_bounds__(256) void ro_shared(
    const ushort_t* __restrict__ featsT, const ushort_t* __restrict__ WroQ,
    float* __restrict__ YR)
{
    int i = blockIdx.x * 256 + threadIdx.x;   // b(2)|px(12)|cu(5)
    int cu = i & 31, px = (i >> 5) & 4095, b = i >> 17;
    int cc = cu >> 2, q = cu & 3;
    int y = px >> 6, xcol = px & 63;
    const ushort_t* wp = WroQ + (size_t)(cc * 4 + q) * 72;
    float wreg[9][8];
#pragma unroll
    for (int t = 0; t < 9; ++t) {
        uint4 wv = *(const uint4*)(wp + t * 8);
        const ushort_t* wq = (const ushort_t*)&wv;
#pragma unroll
        for (int k = 0; k < 8; ++k) wreg[t][k] = h2f(wq[k]);
    }
    const ushort_t* fb = featsT + (size_t)(b * 8 + cc) * 131072 + q * 8;
    float acc = 0.f;
#pragma unroll
    for (int dy = 0; dy < 3; ++dy) {
        int gy = y + dy - 1;
        if ((unsigned)gy >= 64u) continue;
#pragma unroll
        for (int dx = 0; dx < 3; ++dx) {
            int gx = xcol + dx - 1;
            if ((unsigned)gx >= 64u) continue;
            uint4 v = *(const uint4*)(fb + (size_t)(gy * 64 + gx) * 32);
            const ushort_t* vp = (const ushort_t*)&v;
#pragma unroll
            for (int k = 0; k < 8; ++k)
                acc = fmaf(h2f(vp[k]), wreg[dy * 3 + dx][k], acc);
        }
    }
#pragma unroll
    for (int d = 16; d >= 1; d >>= 1) acc += __shfl_down(acc, d, 32);
    if (cu == 0) YR[b * 4096 + px] = acc;
}

// ---- readout per-object part: thread = 8 ci x 9 taps + sigmoid
__global__ __launch_bounds__(256) void ro_obj(
    const ushort_t* __restrict__ S, const ushort_t* __restrict__ WroS,
    const float* __restrict__ ro_b, const float* __restrict__ YR,
    float* __restrict__ out)
{
    int i = blockIdx.x * 256 + threadIdx.x;   // n(5)|px(12)|cu(4)
    int cu = i & 15, px = (i >> 4) & 4095, n = i >> 16;
    int b = n >> 3;
    int cc = cu >> 2, q = cu & 3;
    int y = px >> 6, xcol = px & 63;
    const ushort_t* wp = WroS + (size_t)(cc * 4 + q) * 72;
    float wreg[9][8];
#pragma unroll
    for (int t = 0; t < 9; ++t) {
        uint4 wv = *(const uint4*)(wp + t * 8);
        const ushort_t* wq = (const ushort_t*)&wv;
#pragma unroll
        for (int k = 0; k < 8; ++k) wreg[t][k] = h2f(wq[k]);
    }
    const ushort_t* sb = S + ((size_t)n * 4 + cc) * 131072 + q * 8;
    float acc = 0.f;
#pragma unroll
    for (int dy = 0; dy < 3; ++dy) {
        int gy = y + dy - 1;
        if ((unsigned)gy >= 64u) continue;
#pragma unroll
        for (int dx = 0; dx < 3; ++dx) {
            int gx = xcol + dx - 1;
            if ((unsigned)gx >= 64u) continue;
            uint4 v = *(const uint4*)(sb + (size_t)(gy * 64 + gx) * 32);
            const ushort_t* vp = (const ushort_t*)&v;
#pragma unroll
            for (int k = 0; k < 8; ++k)
                acc = fmaf(h2f(vp[k]), wreg[dy * 3 + dx][k], acc);
        }
    }
#pragma unroll
    for (int d = 8; d >= 1; d >>= 1) acc += __shfl_down(acc, d, 16);
    if (cu == 0) {
        float v = acc + YR[b * 4096 + px] + ro_b[0];
        out[n * 4096 + px] = 1.f / (1.f + __expf(-v));
    }
}

extern "C" void kernel_launch(void* const* d_in, const int* in_sizes, int n_in,
                              void* d_out, int out_size, void* d_ws, size_t ws_size,
                              hipStream_t stream)
{
    const float* feats = (const float*)d_in[0];   // [4,256,64,64]
    const float* masks = (const float*)d_in[1];   // [4,8,64,64]
    const float* enc_w = (const float*)d_in[4];   // [128,257,3,3]
    const float* enc_b = (const float*)d_in[5];
    const float* gcn_w = (const float*)d_in[6];   // [128,256,3,3]
    const float* gcn_b = (const float*)d_in[7];
    const float* ro_w  = (const float*)d_in[8];   // [1,384,3,3]
    const float* ro_b  = (const float*)d_in[9];
    float* out = (float*)d_out;                   // [4,8,64,64]

    // workspace (ushort units; fp32 tail)
    ushort_t* WencF  = (ushort_t*)d_ws;           // 294912
    ushort_t* WgcnS  = WencF + 294912;            // 147456
    ushort_t* WgcnD  = WgcnS + 147456;            // 147456
    ushort_t* WroQ   = WgcnD + 147456;            // 2304
    ushort_t* WroS   = WroQ + 2304;               // 1152
    ushort_t* featsT = WroS + 1152;               // [4][8cc][4096][32]
    ushort_t* Sa     = featsT + 4194304;          // [32][4cc][4096][32]
    ushort_t* Sb     = Sa + 16777216;
    ushort_t* USum   = Sb + 16777216;             // [4][4cc][4096][32]
    ushort_t* U1p16  = USum + 2097152;            // [8kz][4img][4cc][4096][32]
    ushort_t* U2p16  = U1p16 + 16777216;          // [4kz][4img][4cc][4096][32]
    float*    YR     = (float*)(U2p16 + 8388608); // 4*4096 fp32

    dim3 blk(256);

    prep_all<<<3344, blk, 0, stream>>>(feats, enc_w, gcn_w, ro_w,
                                       featsT, WencF, WgcnS, WgcnD, WroQ, WroS);

    // encoder shared conv: 8 fp16 kz-partials, 1024 blocks
    conv_k<1, false><<<dim3(32, 4, 8), blk, 0, stream>>>(
        featsT, WencF, U1p16, nullptr, nullptr, 8);
    enc_obj_sum<<<1024, blk, 0, stream>>>(masks, enc_w, enc_b, U1p16, Sa, USum);

    // step 1: shared partials -> fused object conv -> sum
    conv_k<1, false><<<dim3(32, 4, 4), blk, 0, stream>>>(
        USum, WgcnS, U2p16, nullptr, nullptr, 4);
    conv_k<4, true><<<dim3(32, 32, 1), blk, 0, stream>>>(
        Sa, WgcnD, Sb, U2p16, gcn_b, 4);
    sum8<<<1024, blk, 0, stream>>>(Sb, USum);

    // step 2 (no sum needed afterwards)
    conv_k<1, false><<<dim3(32, 4, 4), blk, 0, stream>>>(
        USum, WgcnS, U2p16, nullptr, nullptr, 4);
    conv_k<4, true><<<dim3(32, 32, 1), blk, 0, stream>>>(
        Sb, WgcnD, Sa, U2p16, gcn_b, 4);

    // readout (final states in Sa)
    ro_shared<<<2048, blk, 0, stream>>>(featsT, WroQ, YR);
    ro_obj<<<8192, blk, 0, stream>>>(Sa, WroS, ro_b, YR, out);
}

// Round 12
// 269.729 us; speedup vs baseline: 1.0117x; 1.0117x over previous
//
#include <hip/hip_runtime.h>
#include <math.h>

// B=4, O=8, C=256, HID=128, H=W=64, STEPS=2
// m97-structure MFMA conv (glds dbuf staging, 1 barrier/chunk) at the ~874TF
// HIP-level plateau. 8-dispatch chain:
//   prep -> encconv(4 kz-partials) -> [enc_obj_sum + ro_shared] ->
//   shconv1 -> objconv1(FUSE) -> shconv2(SUMIN: sums 8 objects in staging) ->
//   objconv2(FUSE) -> ro_obj
// Activations fp16 chunked HWC: x[img][cc][px][ci32] (4KB DMA-able slabs).

typedef unsigned short ushort_t;
typedef _Float16 f16x8 __attribute__((ext_vector_type(8)));
typedef float f32x4 __attribute__((ext_vector_type(4)));

#define GLDS(gsrc, ldst)                                                      \
    __builtin_amdgcn_global_load_lds(                                         \
        (const __attribute__((address_space(1))) unsigned int*)(gsrc),        \
        (__attribute__((address_space(3))) unsigned int*)(ldst), 16, 0, 0)

__device__ __forceinline__ ushort_t f2h(float f) {
    _Float16 h = (_Float16)f;
    return *(ushort_t*)&h;
}
__device__ __forceinline__ float h2f(ushort_t u) {
    _Float16 h = *(_Float16*)&u;
    return (float)h;
}

// ---- merged prep: blocks <1024: feats CHW->chunked HWC; rest: weight packing
__global__ __launch_bounds__(256) void prep_all(
    const float* __restrict__ feats, const float* __restrict__ enc_w,
    const float* __restrict__ gcn_w, const float* __restrict__ ro_w,
    ushort_t* __restrict__ featsT, ushort_t* __restrict__ WencF,
    ushort_t* __restrict__ WgcnS, ushort_t* __restrict__ WgcnD,
    ushort_t* __restrict__ WroQ, ushort_t* __restrict__ WroS)
{
    __shared__ float tile[64][65];
    int bid = blockIdx.x, t = threadIdx.x;
    if (bid < 1024) {                 // feats transform: pt|ct|img
        int pt = bid & 63, ct = (bid >> 6) & 3, img = bid >> 8;
        int px_l = t & 63;
        const float* src = feats + ((size_t)img * 256 + ct * 64) * 4096 + pt * 64;
#pragma unroll
        for (int j = 0; j < 16; ++j) {
            int ci_l = (t >> 6) + j * 4;
            tile[px_l][ci_l] = src[(size_t)ci_l * 4096 + px_l];
        }
        __syncthreads();
        int px = t >> 2;
#pragma unroll
        for (int j = 0; j < 2; ++j) {
            int c8 = ((t & 3) + j * 4) * 8;
            uint4 v; ushort_t* pv = (ushort_t*)&v;
#pragma unroll
            for (int k = 0; k < 8; ++k) pv[k] = f2h(tile[px][c8 + k]);
            int cc = ct * 2 + (c8 >> 5);
            *(uint4*)(featsT + ((size_t)img * 8 + cc) * 131072 +
                      (size_t)(pt * 64 + px) * 32 + (c8 & 31)) = v;
        }
        return;
    }
    int i = (bid - 1024) * 256 + t;
    if (i < 294912) {                 // WencF[t][cc8][co128][ci32]
        int ci32 = i & 31, co = (i >> 5) & 127, tc = i >> 12;
        int tt = tc >> 3, cc = tc & 7, ci = cc * 32 + ci32;
        WencF[i] = f2h(enc_w[(co * 257 + ci) * 9 + tt]);
    } else if (i < 442368) {          // WgcnS[t][cc4][co128][ci32]
        int j = i - 294912;
        int ci32 = j & 31, co = (j >> 5) & 127, tc = j >> 12;
        int tt = tc >> 2, cc = tc & 3, ci = cc * 32 + ci32;
        WgcnS[j] = f2h(gcn_w[(co * 256 + 128 + ci) * 9 + tt]);
    } else if (i < 589824) {          // WgcnD = W1 - W2
        int j = i - 442368;
        int ci32 = j & 31, co = (j >> 5) & 127, tc = j >> 12;
        int tt = tc >> 2, cc = tc & 3, ci = cc * 32 + ci32;
        WgcnD[j] = f2h(gcn_w[(co * 256 + ci) * 9 + tt] -
                       gcn_w[(co * 256 + 128 + ci) * 9 + tt]);
    } else if (i < 592128) {          // WroQ[8cc][4q][9t][8k]
        int j = i - 589824;
        int k = j & 7, r = j >> 3;
        int tt = r % 9, cq = r / 9, q = cq & 3, cc = cq >> 2;
        WroQ[j] = f2h(ro_w[(cc * 32 + q * 8 + k) * 9 + tt]);
    } else if (i < 593280) {          // WroS[4cc][4q][9t][8k]
        int j = i - 592128;
        int k = j & 7, r = j >> 3;
        int tt = r % 9, cq = r / 9, q = cq & 3, cc = cq >> 2;
        WroS[j] = f2h(ro_w[(256 + cc * 32 + q * 8 + k) * 9 + tt]);
    }
}

// ---- conv (m97 structure). grid (32 rowpairs, nimg, kz). Block: 128co x 128px,
// 4 waves (cg,pg); wave 64co x 64px. Out: fp16 chunked raw at slot kz*gridDim.y+img.
// FUSE:  epilogue = relu(raw + sum4(addp partials) + bias) (gcn object conv).
// SUMIN: act staging sums 8 objects (img = batch; object stride ncc_img*131072).
template<int NCCBLK, bool FUSE, bool SUMIN>
__global__ __launch_bounds__(256, 3) void conv_k(
    const ushort_t* __restrict__ x, const ushort_t* __restrict__ W,
    ushort_t* __restrict__ out,
    const ushort_t* __restrict__ addp, const float* __restrict__ bias,
    int ncc_img)
{
    __shared__ ushort_t raw[25088];           // 50176 B
    ushort_t* xs = raw;                       // 2 x [4 rows][66 cols][32ci]
    ushort_t* wlds = raw + 16896;             // 2 x [128 co][32ci]
    ushort_t* eb16 = raw;                     // epilogue overlay [64][136]

    const int rp = blockIdx.x, img = blockIdx.y, kz = blockIdx.z;
    const int row0 = rp * 2;
    const int cc0 = kz * NCCBLK;
    const int nchunk = 9 * NCCBLK;
    const int tid = threadIdx.x;
    const int w = tid >> 6, lane = tid & 63, lq = lane >> 4, lr = lane & 15;
    const int cg = w >> 1, pg = w & 1;

    const size_t objstride = (size_t)ncc_img * 131072;
    const ushort_t* xb = SUMIN ? x + (size_t)img * 8 * objstride
                               : x + (size_t)img * objstride;
    const int aoff0 = (cg * 64 + lr) * 32 + lq * 8;

    // zero halo columns (0 and 65) of both act buffers, once
    if (tid < 64) {
        int b = tid >> 5, r = (tid >> 3) & 3, c = (tid >> 2) & 1, s = tid & 3;
        *(uint4*)(xs + b * 8448 + r * 2112 + (c ? 65 : 0) * 32 + s * 8) =
            make_uint4(0, 0, 0, 0);
    }

    f32x4 acc[4][4];
#pragma unroll
    for (int a = 0; a < 4; ++a)
#pragma unroll
        for (int p = 0; p < 4; ++p) acc[a][p] = (f32x4){0.f, 0.f, 0.f, 0.f};

    const int gy = row0 - 1 + w;
    const bool row_ok = (unsigned)gy < 64u;
#define STAGE_ACT(cc_, buf_)                                                    \
    {                                                                           \
        ushort_t* dst = xs + (buf_) * 8448 + w * 2112 + 32;                     \
        if (row_ok) {                                                           \
            const ushort_t* src = xb + (size_t)(cc_) * 131072 + (size_t)gy * 2048; \
            if constexpr (SUMIN) {                                              \
                _Pragma("unroll")                                               \
                for (int u_ = 0; u_ < 4; ++u_) {                                \
                    f16x8 a_ = {0, 0, 0, 0, 0, 0, 0, 0};                        \
                    _Pragma("unroll")                                           \
                    for (int o_ = 0; o_ < 8; ++o_)                              \
                        a_ = a_ + *(const f16x8*)(src + (size_t)o_ * objstride + \
                                                  u_ * 512 + lane * 8);         \
                    *(f16x8*)(dst + u_ * 512 + lane * 8) = a_;                  \
                }                                                               \
            } else {                                                            \
                GLDS(src + 0 * 512 + lane * 8, dst + 0 * 512);                  \
                GLDS(src + 1 * 512 + lane * 8, dst + 1 * 512);                  \
                GLDS(src + 2 * 512 + lane * 8, dst + 2 * 512);                  \
                GLDS(src + 3 * 512 + lane * 8, dst + 3 * 512);                  \
            }                                                                   \
        } else {                                                                \
            *(uint4*)(dst + 0 * 512 + lane * 8) = make_uint4(0, 0, 0, 0);       \
            *(uint4*)(dst + 1 * 512 + lane * 8) = make_uint4(0, 0, 0, 0);       \
            *(uint4*)(dst + 2 * 512 + lane * 8) = make_uint4(0, 0, 0, 0);       \
            *(uint4*)(dst + 3 * 512 + lane * 8) = make_uint4(0, 0, 0, 0);       \
        }                                                                       \
    }
#define STAGE_W(t_, cc_, buf_)                                                  \
    {                                                                           \
        const ushort_t* src = W + ((size_t)((t_) * ncc_img + (cc_)) * 4096);    \
        ushort_t* dst = wlds + (buf_) * 4096;                                   \
        GLDS(src + (w * 2 + 0) * 512 + lane * 8, dst + (w * 2 + 0) * 512);      \
        GLDS(src + (w * 2 + 1) * 512 + lane * 8, dst + (w * 2 + 1) * 512);      \
    }

    STAGE_ACT(cc0, 0);
    STAGE_W(0, cc0, 0);

    int kc = 0;
#pragma unroll
    for (int ccl = 0; ccl < NCCBLK; ++ccl) {
        const int cc = cc0 + ccl;
        const int xbuf = ccl & 1;
#pragma unroll
        for (int t = 0; t < 9; ++t, ++kc) {
            __syncthreads();
            if (kc + 1 < nchunk) {
                if (t == 8) {
                    STAGE_W(0, cc + 1, (kc + 1) & 1);
                    STAGE_ACT(cc + 1, (ccl + 1) & 1);
                } else {
                    STAGE_W(t + 1, cc, (kc + 1) & 1);
                }
            }
            const int dy = t / 3, dx = t - 3 * dy;
            const ushort_t* wl = wlds + (kc & 1) * 4096 + aoff0;
            const ushort_t* xl = xs + xbuf * 8448 + (pg + dy) * 2112 + (dx + lr) * 32 + lq * 8;
            f16x8 A0 = *(const f16x8*)(wl);
            f16x8 A1 = *(const f16x8*)(wl + 512);
            f16x8 A2 = *(const f16x8*)(wl + 1024);
            f16x8 A3 = *(const f16x8*)(wl + 1536);
#pragma unroll
            for (int p = 0; p < 4; ++p) {
                f16x8 Bf = *(const f16x8*)(xl + p * 512);
                acc[0][p] = __builtin_amdgcn_mfma_f32_16x16x32_f16(A0, Bf, acc[0][p], 0, 0, 0);
                acc[1][p] = __builtin_amdgcn_mfma_f32_16x16x32_f16(A1, Bf, acc[1][p], 0, 0, 0);
                acc[2][p] = __builtin_amdgcn_mfma_f32_16x16x32_f16(A2, Bf, acc[2][p], 0, 0, 0);
                acc[3][p] = __builtin_amdgcn_mfma_f32_16x16x32_f16(A3, Bf, acc[3][p], 0, 0, 0);
            }
        }
    }

    // ---- epilogue via LDS transpose, fp16 chunked out
    ushort_t* obase = out + (size_t)(kz * gridDim.y + img) * 524288;
    const int b4 = img >> 3;                  // batch (FUSE only)
#pragma unroll
    for (int r = 0; r < 2; ++r) {
        __syncthreads();
        if (pg == r) {
#pragma unroll
            for (int cf = 0; cf < 4; ++cf)
#pragma unroll
                for (int pf = 0; pf < 4; ++pf) {
                    int px = pf * 16 + lr;
                    int co_l = cg * 64 + cf * 16 + lq * 4;
                    ushort_t pk[4];
#pragma unroll
                    for (int j = 0; j < 4; ++j) pk[j] = f2h(acc[cf][pf][j]);
                    *(uint2*)(eb16 + px * 136 + co_l) = *(uint2*)pk;
                }
        }
        __syncthreads();
#pragma unroll
        for (int k2 = 0; k2 < 4; ++k2) {
            int i = tid + k2 * 256;
            int px = i >> 4, c16 = i & 15;
            int pxg = (row0 + r) * 64 + px;
            size_t coff = (size_t)(c16 >> 2) * 131072 + (size_t)pxg * 32 + (c16 & 3) * 8;
            uint4 v = *(uint4*)(eb16 + px * 136 + c16 * 8);
            if constexpr (FUSE) {
                const ushort_t* vp = (const ushort_t*)&v;
                float vv[8];
#pragma unroll
                for (int k = 0; k < 8; ++k) vv[k] = h2f(vp[k]) + bias[c16 * 8 + k];
#pragma unroll
                for (int p = 0; p < 4; ++p) {
                    uint4 av = *(const uint4*)(addp + (size_t)(p * 4 + b4) * 524288 + coff);
                    const ushort_t* ap = (const ushort_t*)&av;
#pragma unroll
                    for (int k = 0; k < 8; ++k) vv[k] += h2f(ap[k]);
                }
                uint4 sv; ushort_t* sp = (ushort_t*)&sv;
#pragma unroll
                for (int k = 0; k < 8; ++k) sp[k] = f2h(fmaxf(vv[k], 0.f));
                *(uint4*)(obase + coff) = sv;
            } else {
                *(uint4*)(obase + coff) = v;
            }
        }
    }
#undef STAGE_ACT
#undef STAGE_W
}

// ---- merged: bid<1024: encoder per-object + object-sum (4 fp16 kz-partials);
//              bid>=1024: readout shared part (2048 blocks)
__global__ __launch_bounds__(256) void enc_obj_ro(
    const float* __restrict__ masks, const float* __restrict__ enc_w,
    const float* __restrict__ enc_b, const ushort_t* __restrict__ U1p,
    const ushort_t* __restrict__ featsT, const ushort_t* __restrict__ WroQ,
    ushort_t* __restrict__ S, ushort_t* __restrict__ USum,
    float* __restrict__ YR)
{
    int bid = blockIdx.x, tid = threadIdx.x;
    if (bid >= 1024) {
        // ---- ro_shared: i = b(2)|px(12)|cu(5)
        int i = (bid - 1024) * 256 + tid;
        int cu = i & 31, px = (i >> 5) & 4095, b = i >> 17;
        int cc = cu >> 2, q = cu & 3;
        int y = px >> 6, xcol = px & 63;
        const ushort_t* wp = WroQ + (size_t)(cc * 4 + q) * 72;
        float wreg[9][8];
#pragma unroll
        for (int t = 0; t < 9; ++t) {
            uint4 wv = *(const uint4*)(wp + t * 8);
            const ushort_t* wq = (const ushort_t*)&wv;
#pragma unroll
            for (int k = 0; k < 8; ++k) wreg[t][k] = h2f(wq[k]);
        }
        const ushort_t* fb = featsT + (size_t)(b * 8 + cc) * 131072 + q * 8;
        float acc = 0.f;
#pragma unroll
        for (int dy = 0; dy < 3; ++dy) {
            int gy = y + dy - 1;
            if ((unsigned)gy >= 64u) continue;
#pragma unroll
            for (int dx = 0; dx < 3; ++dx) {
                int gx = xcol + dx - 1;
                if ((unsigned)gx >= 64u) continue;
                uint4 v = *(const uint4*)(fb + (size_t)(gy * 64 + gx) * 32);
                const ushort_t* vp = (const ushort_t*)&v;
#pragma unroll
                for (int k = 0; k < 8; ++k)
                    acc = fmaf(h2f(vp[k]), wreg[dy * 3 + dx][k], acc);
            }
        }
#pragma unroll
        for (int d = 16; d >= 1; d >>= 1) acc += __shfl_down(acc, d, 32);
        if (cu == 0) YR[b * 4096 + px] = acc;
        return;
    }
    // ---- enc_obj_sum: i = b(2)|cc(2)|px(12)|s(2)
    int i = bid * 256 + tid;
    int s = i & 3, px = (i >> 2) & 4095, cc = (i >> 14) & 3, b = i >> 16;
    int co = cc * 32 + s * 8;
    int y = px >> 6, xx = px & 63;
    size_t coff = (size_t)cc * 131072 + (size_t)px * 32 + s * 8;
    float base[8];
#pragma unroll
    for (int k = 0; k < 8; ++k) base[k] = enc_b[co + k];
#pragma unroll
    for (int p = 0; p < 4; ++p) {
        uint4 v = *(const uint4*)(U1p + (size_t)(p * 4 + b) * 524288 + coff);
        const ushort_t* vp = (const ushort_t*)&v;
#pragma unroll
        for (int k = 0; k < 8; ++k) base[k] += h2f(vp[k]);
    }
    float wm[8][9];
#pragma unroll
    for (int k = 0; k < 8; ++k) {
        const float* wp = enc_w + (size_t)((co + k) * 257 + 256) * 9;
#pragma unroll
        for (int t = 0; t < 9; ++t) wm[k][t] = wp[t];
    }
    float sacc[8] = {0, 0, 0, 0, 0, 0, 0, 0};
#pragma unroll
    for (int o = 0; o < 8; ++o) {
        const float* m = masks + (size_t)(b * 8 + o) * 4096;
        float mt[9];
#pragma unroll
        for (int dy = 0; dy < 3; ++dy)
#pragma unroll
            for (int dx = 0; dx < 3; ++dx) {
                int gy_ = y + dy - 1, gx = xx + dx - 1;
                mt[dy * 3 + dx] =
                    ((unsigned)gy_ < 64u && (unsigned)gx < 64u) ? m[gy_ * 64 + gx] : 0.f;
            }
        uint4 sv; ushort_t* sp = (ushort_t*)&sv;
#pragma unroll
        for (int k = 0; k < 8; ++k) {
            float acc = base[k];
#pragma unroll
            for (int t = 0; t < 9; ++t) acc = fmaf(mt[t], wm[k][t], acc);
            acc = fmaxf(acc, 0.f);
            sacc[k] += acc;
            sp[k] = f2h(acc);
        }
        *(uint4*)(S + (size_t)(b * 8 + o) * 524288 + coff) = sv;
    }
    uint4 sv; ushort_t* sp = (ushort_t*)&sv;
#pragma unroll
    for (int k = 0; k < 8; ++k) sp[k] = f2h(sacc[k]);
    *(uint4*)(USum + (size_t)b * 524288 + coff) = sv;
}

// ---- readout per-object part: thread = 8 ci x 9 taps + sigmoid
__global__ __launch_bounds__(256) void ro_obj(
    const ushort_t* __restrict__ S, const ushort_t* __restrict__ WroS,
    const float* __restrict__ ro_b, const float* __restrict__ YR,
    float* __restrict__ out)
{
    int i = blockIdx.x * 256 + threadIdx.x;   // n(5)|px(12)|cu(4)
    int cu = i & 15, px = (i >> 4) & 4095, n = i >> 16;
    int b = n >> 3;
    int cc = cu >> 2, q = cu & 3;
    int y = px >> 6, xcol = px & 63;
    const ushort_t* wp = WroS + (size_t)(cc * 4 + q) * 72;
    float wreg[9][8];
#pragma unroll
    for (int t = 0; t < 9; ++t) {
        uint4 wv = *(const uint4*)(wp + t * 8);
        const ushort_t* wq = (const ushort_t*)&wv;
#pragma unroll
        for (int k = 0; k < 8; ++k) wreg[t][k] = h2f(wq[k]);
    }
    const ushort_t* sb = S + ((size_t)n * 4 + cc) * 131072 + q * 8;
    float acc = 0.f;
#pragma unroll
    for (int dy = 0; dy < 3; ++dy) {
        int gy = y + dy - 1;
        if ((unsigned)gy >= 64u) continue;
#pragma unroll
        for (int dx = 0; dx < 3; ++dx) {
            int gx = xcol + dx - 1;
            if ((unsigned)gx >= 64u) continue;
            uint4 v = *(const uint4*)(sb + (size_t)(gy * 64 + gx) * 32);
            const ushort_t* vp = (const ushort_t*)&v;
#pragma unroll
            for (int k = 0; k < 8; ++k)
                acc = fmaf(h2f(vp[k]), wreg[dy * 3 + dx][k], acc);
        }
    }
#pragma unroll
    for (int d = 8; d >= 1; d >>= 1) acc += __shfl_down(acc, d, 16);
    if (cu == 0) {
        float v = acc + YR[b * 4096 + px] + ro_b[0];
        out[n * 4096 + px] = 1.f / (1.f + __expf(-v));
    }
}

extern "C" void kernel_launch(void* const* d_in, const int* in_sizes, int n_in,
                              void* d_out, int out_size, void* d_ws, size_t ws_size,
                              hipStream_t stream)
{
    const float* feats = (const float*)d_in[0];   // [4,256,64,64]
    const float* masks = (const float*)d_in[1];   // [4,8,64,64]
    const float* enc_w = (const float*)d_in[4];   // [128,257,3,3]
    const float* enc_b = (const float*)d_in[5];
    const float* gcn_w = (const float*)d_in[6];   // [128,256,3,3]
    const float* gcn_b = (const float*)d_in[7];
    const float* ro_w  = (const float*)d_in[8];   // [1,384,3,3]
    const float* ro_b  = (const float*)d_in[9];
    float* out = (float*)d_out;                   // [4,8,64,64]

    // workspace (ushort units; fp32 tail)
    ushort_t* WencF  = (ushort_t*)d_ws;           // 294912
    ushort_t* WgcnS  = WencF + 294912;            // 147456
    ushort_t* WgcnD  = WgcnS + 147456;            // 147456
    ushort_t* WroQ   = WgcnD + 147456;            // 2304
    ushort_t* WroS   = WroQ + 2304;               // 1152
    ushort_t* featsT = WroS + 1152;               // [4][8cc][4096][32]
    ushort_t* Sa     = featsT + 4194304;          // [32][4cc][4096][32]
    ushort_t* Sb     = Sa + 16777216;
    ushort_t* USum   = Sb + 16777216;             // [4][4cc][4096][32]
    ushort_t* U1p16  = USum + 2097152;            // [4kz][4img][4cc][4096][32]
    ushort_t* U2p16  = U1p16 + 8388608;           // [4kz][4img][4cc][4096][32]
    float*    YR     = (float*)(U2p16 + 8388608); // 4*4096 fp32

    dim3 blk(256);

    prep_all<<<3344, blk, 0, stream>>>(feats, enc_w, gcn_w, ro_w,
                                       featsT, WencF, WgcnS, WgcnD, WroQ, WroS);

    // encoder shared conv: 4 fp16 kz-partials (K=576 each), 512 blocks
    conv_k<2, false, false><<<dim3(32, 4, 4), blk, 0, stream>>>(
        featsT, WencF, U1p16, nullptr, nullptr, 8);
    // enc per-object + object-sum, fused with ro_shared (independent blocks)
    enc_obj_ro<<<3072, blk, 0, stream>>>(masks, enc_w, enc_b, U1p16,
                                         featsT, WroQ, Sa, USum, YR);

    // step 1: shared partials -> fused object conv
    conv_k<1, false, false><<<dim3(32, 4, 4), blk, 0, stream>>>(
        USum, WgcnS, U2p16, nullptr, nullptr, 4);
    conv_k<4, true, false><<<dim3(32, 32, 1), blk, 0, stream>>>(
        Sa, WgcnD, Sb, U2p16, gcn_b, 4);

    // step 2: shared conv sums the 8 objects during staging (deletes sum8)
    conv_k<1, false, true><<<dim3(32, 4, 4), blk, 0, stream>>>(
        Sb, WgcnS, U2p16, nullptr, nullptr, 4);
    conv_k<4, true, false><<<dim3(32, 32, 1), blk, 0, stream>>>(
        Sb, WgcnD, Sa, U2p16, gcn_b, 4);

    // readout (final states in Sa)
    ro_obj<<<8192, blk, 0, stream>>>(Sa, WroS, ro_b, YR, out);
}